// Round 3
// baseline (2357.060 us; speedup 1.0000x reference)
//
#include <hip/hip_runtime.h>
#include <math.h>

#define EPS 1e-4f
#define BN_EPS 1e-3f
#define LN_EPS 1e-3f

// ---------------- K1: sp = BN(feat @ W_pre + b_pre)  (+ zeroing of reduction accums) ----------------
// 16 rows/block, 256 threads: thread = (rowgroup of 8 rows) x (1 col)
__global__ __launch_bounds__(256) void k_pre(
    const float* __restrict__ feat, const float* __restrict__ W_pre,
    const float* __restrict__ b_pre, const float* __restrict__ g_pre,
    const float* __restrict__ be_pre, const float* __restrict__ m_pre,
    const float* __restrict__ v_pre, float* __restrict__ sp,
    float* __restrict__ accums /* 2176 floats to zero */)
{
    __shared__ __align__(16) float ft[16][64];
    int tid = threadIdx.x;
    int r0 = blockIdx.x * 16;
    if (blockIdx.x == 0){
        for (int i = tid; i < 2176; i += 256) accums[i] = 0.f;
    }
    {
        const float4* src = (const float4*)(feat + (size_t)r0 * 64);
        ((float4*)ft)[tid] = src[tid];   // 256 float4 = 16x64 floats
    }
    __syncthreads();
    int c = tid & 127;
    int rg = tid >> 7;
    float acc[8] = {0.f,0.f,0.f,0.f,0.f,0.f,0.f,0.f};
    #pragma unroll
    for (int k = 0; k < 64; k += 4){
        float w0 = W_pre[(k+0)*128 + c];
        float w1 = W_pre[(k+1)*128 + c];
        float w2 = W_pre[(k+2)*128 + c];
        float w3 = W_pre[(k+3)*128 + c];
        #pragma unroll
        for (int j = 0; j < 8; j++){
            float4 a = *(const float4*)&ft[rg*8 + j][k];
            acc[j] += a.x*w0 + a.y*w1 + a.z*w2 + a.w*w3;
        }
    }
    float aa = g_pre[c] * rsqrtf(v_pre[c] + BN_EPS);
    float cc = (b_pre[c] - m_pre[c]) * aa + be_pre[c];
    #pragma unroll
    for (int j = 0; j < 8; j++){
        size_t row = r0 + rg*8 + j;
        sp[row*128 + c] = acc[j]*aa + cc;
    }
}

// ---------------- K2: fused pe + qkv + elementwise ----------------
// 32 rows/block, 256 threads: thread = (rowgroup of 16 rows) x (1 channel c)
__global__ __launch_bounds__(256) void k_qkv(
    const float* __restrict__ sp, const int* __restrict__ indices,
    const float* __restrict__ Wp1, const float* __restrict__ bp1,
    const float* __restrict__ g_pe, const float* __restrict__ be_pe,
    const float* __restrict__ m_pe, const float* __restrict__ v_pe,
    const float* __restrict__ Wp2, const float* __restrict__ bp2,
    const float* __restrict__ W_qkv, const float* __restrict__ b_qkv,
    const float* __restrict__ scale_p,
    float* __restrict__ qb, float* __restrict__ kb, float* __restrict__ vb)
{
    __shared__ __align__(16) float spt[32][128];
    __shared__ __align__(16) float peh[32][128];
    __shared__ float xyzs[32][3];
    int tid = threadIdx.x;
    int r0 = blockIdx.x * 32;
    {
        const float4* src = (const float4*)(sp + (size_t)r0 * 128);
        float4* dst = (float4*)&spt[0][0];
        #pragma unroll
        for (int u = 0; u < 4; u++) dst[tid + 256*u] = src[tid + 256*u];
    }
    if (tid < 96){
        int r = tid / 3, d = tid % 3;
        xyzs[r][d] = (float)indices[(size_t)(r0 + r)*4 + 1 + d];
    }
    __syncthreads();
    // phase A: peh = relu(BN(xyz @ Wp1 + bp1))
    #pragma unroll
    for (int u = 0; u < 16; u++){
        int oi = tid + 256*u;          // 0..4095
        int r = oi >> 7, c = oi & 127;
        float dot = xyzs[r][0]*Wp1[c] + xyzs[r][1]*Wp1[128+c] + xyzs[r][2]*Wp1[256+c] + bp1[c];
        float aa = g_pe[c] * rsqrtf(v_pe[c] + BN_EPS);
        float t = (dot - m_pe[c])*aa + be_pe[c];
        peh[r][c] = fmaxf(t, 0.f);
    }
    __syncthreads();
    int c = tid & 127, rg = tid >> 7;
    float accq[16] = {0}, acck[16] = {0}, accv[16] = {0}, accp[16] = {0};
    for (int k = 0; k < 128; k += 4){
        float wq[4], wk[4], wv[4], wp[4];
        #pragma unroll
        for (int i = 0; i < 4; i++){
            wq[i] = W_qkv[(size_t)(k+i)*384 + c];
            wk[i] = W_qkv[(size_t)(k+i)*384 + 128 + c];
            wv[i] = W_qkv[(size_t)(k+i)*384 + 256 + c];
            wp[i] = Wp2[(k+i)*128 + c];
        }
        #pragma unroll
        for (int j = 0; j < 16; j++){
            float4 a = *(const float4*)&spt[rg*16 + j][k];
            accq[j] += a.x*wq[0] + a.y*wq[1] + a.z*wq[2] + a.w*wq[3];
            acck[j] += a.x*wk[0] + a.y*wk[1] + a.z*wk[2] + a.w*wk[3];
            accv[j] += a.x*wv[0] + a.y*wv[1] + a.z*wv[2] + a.w*wv[3];
            float4 p = *(const float4*)&peh[rg*16 + j][k];
            accp[j] += p.x*wp[0] + p.y*wp[1] + p.z*wp[2] + p.w*wp[3];
        }
    }
    float bq = b_qkv[c], bk = b_qkv[128 + c], bv = b_qkv[256 + c], bp = bp2[c];
    float sx = scale_p[c];
    float sc = (sx > 20.f) ? sx : log1pf(expf(sx));
    float inv = 1.f / sc;
    #pragma unroll
    for (int j = 0; j < 16; j++){
        size_t row = r0 + rg*16 + j;
        float pe = accp[j] + bp;
        float qv = (fmaxf(accq[j] + bq, 0.f) + EPS) * inv;
        float kv = (fmaxf(acck[j] + bk + pe, 0.f) + EPS) * inv;
        qb[row*128 + c] = qv;
        kb[row*128 + c] = kv;
        vb[row*128 + c] = accv[j] + bv;
    }
}

// ---------------- K2b: ksum[h][e], kv[h][e][f] reductions ----------------
__global__ __launch_bounds__(256) void k_red(
    const float* __restrict__ kb, const float* __restrict__ vb,
    float* __restrict__ ksum, float* __restrict__ kvm, int ntiles)
{
    __shared__ __align__(16) float kt[16][128];
    __shared__ __align__(16) float vt[16][128];
    int tid = threadIdx.x;
    int he = tid & 127, fh = tid >> 7;
    int h = he >> 4;
    float akv[8] = {0,0,0,0,0,0,0,0};
    float aks = 0.f;
    for (int ti = blockIdx.x; ti < ntiles; ti += gridDim.x){
        size_t base = (size_t)ti * 16 * 128;
        const float4* ks_ = (const float4*)(kb + base);
        const float4* vs_ = (const float4*)(vb + base);
        float4* kd = (float4*)&kt[0][0];
        float4* vd = (float4*)&vt[0][0];
        __syncthreads();
        kd[tid] = ks_[tid]; kd[tid + 256] = ks_[tid + 256];
        vd[tid] = vs_[tid]; vd[tid + 256] = vs_[tid + 256];
        __syncthreads();
        #pragma unroll 4
        for (int r = 0; r < 16; r++){
            float kval = kt[r][he];
            const float* vr = &vt[r][h*16 + fh*8];
            float4 v0 = *(const float4*)vr;
            float4 v1 = *(const float4*)(vr + 4);
            akv[0] += kval*v0.x; akv[1] += kval*v0.y; akv[2] += kval*v0.z; akv[3] += kval*v0.w;
            akv[4] += kval*v1.x; akv[5] += kval*v1.y; akv[6] += kval*v1.z; akv[7] += kval*v1.w;
            if (fh == 0) aks += kval;
        }
    }
    #pragma unroll
    for (int j = 0; j < 8; j++) atomicAdd(&kvm[he*16 + fh*8 + j], akv[j]);
    if (fh == 0) atomicAdd(&ksum[he], aks);
}

// ---------------- K4: 27-tap gather conv (conv + b_dwc only) ----------------
// 64 rows/block, 256 threads; thread tile = 8 rows x 4 cols.
// v tile in LDS (gather); weights streamed from L1/L2 (all blocks share the
// same 27x64KB panels -> L2-resident). LDS ~39KB -> 4 blocks/CU.
__global__ __launch_bounds__(256) void k_conv(
    const float* __restrict__ vb, const int* __restrict__ nbr,
    const float* __restrict__ W_dwc, const float* __restrict__ b_dwc,
    float* __restrict__ xb)
{
    __shared__ __align__(16) float vt[64][128];   // 32 KB
    __shared__ int nbT[27][64];                   // 6.9 KB
    int tid = threadIdx.x;
    int r0 = blockIdx.x * 64;
    for (int i = tid; i < 27*64; i += 256){
        int t = i >> 6, r = i & 63;
        nbT[t][r] = nbr[(size_t)(r0 + r)*27 + t];
    }
    int tr = tid >> 5, tc = tid & 31;
    float acc[8][4];
    {
        float4 bd = *(const float4*)&b_dwc[tc*4];
        #pragma unroll
        for (int j = 0; j < 8; j++){
            acc[j][0] = bd.x; acc[j][1] = bd.y; acc[j][2] = bd.z; acc[j][3] = bd.w;
        }
    }
    for (int t = 0; t < 27; t++){
        __syncthreads();                       // prev compute done (and nbT ready on t=0)
        #pragma unroll
        for (int s = 0; s < 8; s++){
            int r = tr + 8*s;
            int idx = nbT[t][r];
            float4 val = make_float4(0.f,0.f,0.f,0.f);
            if (idx >= 0) val = *(const float4*)&vb[(size_t)idx*128 + tc*4];
            *(float4*)&vt[r][tc*4] = val;
        }
        __syncthreads();
        const float* Wt = W_dwc + (size_t)t * 16384;
        #pragma unroll 2
        for (int k4 = 0; k4 < 32; k4++){
            int kk = k4*4;
            float4 w0 = *(const float4*)&Wt[(kk+0)*128 + tc*4];
            float4 w1 = *(const float4*)&Wt[(kk+1)*128 + tc*4];
            float4 w2 = *(const float4*)&Wt[(kk+2)*128 + tc*4];
            float4 w3 = *(const float4*)&Wt[(kk+3)*128 + tc*4];
            #pragma unroll
            for (int j = 0; j < 8; j++){
                float4 a = *(const float4*)&vt[tr*8 + j][kk];
                acc[j][0] += a.x*w0.x + a.y*w1.x + a.z*w2.x + a.w*w3.x;
                acc[j][1] += a.x*w0.y + a.y*w1.y + a.z*w2.y + a.w*w3.y;
                acc[j][2] += a.x*w0.z + a.y*w1.z + a.z*w2.z + a.w*w3.z;
                acc[j][3] += a.x*w0.w + a.y*w1.w + a.z*w2.w + a.w*w3.w;
            }
        }
    }
    #pragma unroll
    for (int j = 0; j < 8; j++){
        size_t row = r0 + tr*8 + j;
        *(float4*)&xb[row*128 + tc*4] = make_float4(acc[j][0], acc[j][1], acc[j][2], acc[j][3]);
    }
}

// ---------------- K5: out = LN( (attn + conv) @ W_proj + b_proj + sp ) ----------------
// 16 rows/block; thread = (rowgroup of 4 rows) x (2 cols); one wave owns 4 rows.
__global__ __launch_bounds__(256) void k_out(
    const float* __restrict__ xb, const float* __restrict__ qb,
    const float* __restrict__ ksum, const float* __restrict__ kvm,
    const float* __restrict__ W_proj, const float* __restrict__ b_proj,
    const float* __restrict__ sp, const float* __restrict__ g_n1,
    const float* __restrict__ b_n1, float* __restrict__ out)
{
    __shared__ __align__(16) float yt[16][128];
    __shared__ __align__(16) float qt[16][128];
    __shared__ float kvl[2048];
    __shared__ float ksl[128];
    int tid = threadIdx.x;
    int r0 = blockIdx.x * 16;
    {
        const float4* srcy = (const float4*)(xb + (size_t)r0 * 128);
        const float4* srcq = (const float4*)(qb + (size_t)r0 * 128);
        float4* dsty = (float4*)&yt[0][0];
        float4* dstq = (float4*)&qt[0][0];
        dsty[tid] = srcy[tid]; dsty[tid + 256] = srcy[tid + 256];
        dstq[tid] = srcq[tid]; dstq[tid + 256] = srcq[tid + 256];
    }
    #pragma unroll
    for (int u = 0; u < 8; u++) kvl[tid + 256*u] = kvm[tid + 256*u];
    if (tid < 128) ksl[tid] = ksum[tid];
    __syncthreads();

    int c2 = (tid & 63) * 2;
    int rg = tid >> 6;
    // ---- attention apply: y = attn + conv, written back into yt ----
    {
        int h = c2 >> 4, f0 = c2 & 15;
        float kv0[16], kv1[16], ks[16];
        #pragma unroll
        for (int e = 0; e < 16; e++){
            kv0[e] = kvl[(h*16 + e)*16 + f0];
            kv1[e] = kvl[(h*16 + e)*16 + f0 + 1];
            ks[e]  = ksl[h*16 + e];
        }
        float y[4][2];
        #pragma unroll
        for (int j = 0; j < 4; j++){
            int r = rg*4 + j;
            float zd = 0.f, x0 = 0.f, x1 = 0.f;
            #pragma unroll
            for (int e = 0; e < 16; e++){
                float qe = qt[r][h*16 + e];
                zd += qe * ks[e];
                x0 += qe * kv0[e];
                x1 += qe * kv1[e];
            }
            float iz = 1.f / (zd + EPS);
            y[j][0] = x0*iz + yt[r][c2];
            y[j][1] = x1*iz + yt[r][c2+1];
        }
        #pragma unroll
        for (int j = 0; j < 4; j++){
            yt[rg*4 + j][c2]     = y[j][0];
            yt[rg*4 + j][c2 + 1] = y[j][1];
        }
    }
    __syncthreads();
    // ---- proj + residual + LN ----
    float acc[4][2] = {{0,0},{0,0},{0,0},{0,0}};
    for (int k = 0; k < 128; k += 4){
        float2 w0 = *(const float2*)&W_proj[(k+0)*128 + c2];
        float2 w1 = *(const float2*)&W_proj[(k+1)*128 + c2];
        float2 w2 = *(const float2*)&W_proj[(k+2)*128 + c2];
        float2 w3 = *(const float2*)&W_proj[(k+3)*128 + c2];
        #pragma unroll
        for (int j = 0; j < 4; j++){
            float4 a = *(const float4*)&yt[rg*4 + j][k];
            acc[j][0] += a.x*w0.x + a.y*w1.x + a.z*w2.x + a.w*w3.x;
            acc[j][1] += a.x*w0.y + a.y*w1.y + a.z*w2.y + a.w*w3.y;
        }
    }
    float bp0 = b_proj[c2], bp1_ = b_proj[c2+1];
    float g0 = g_n1[c2], g1 = g_n1[c2+1], B0 = b_n1[c2], B1 = b_n1[c2+1];
    float z[4][2], s[4], ss[4];
    #pragma unroll
    for (int j = 0; j < 4; j++){
        size_t row = r0 + rg*4 + j;
        float2 spv = *(const float2*)&sp[row*128 + c2];
        float z0 = acc[j][0] + bp0 + spv.x;
        float z1 = acc[j][1] + bp1_ + spv.y;
        z[j][0] = z0; z[j][1] = z1;
        s[j] = z0 + z1; ss[j] = z0*z0 + z1*z1;
    }
    #pragma unroll
    for (int m = 1; m < 64; m <<= 1){
        #pragma unroll
        for (int j = 0; j < 4; j++){
            s[j]  += __shfl_xor(s[j],  m, 64);
            ss[j] += __shfl_xor(ss[j], m, 64);
        }
    }
    #pragma unroll
    for (int j = 0; j < 4; j++){
        size_t row = r0 + rg*4 + j;
        float mu = s[j] * (1.f/128.f);
        float var = ss[j] * (1.f/128.f) - mu*mu;
        float rstd = rsqrtf(var + LN_EPS);
        float2 o;
        o.x = (z[j][0] - mu)*rstd*g0 + B0;
        o.y = (z[j][1] - mu)*rstd*g1 + B1;
        *(float2*)&out[row*128 + c2] = o;
    }
}

extern "C" void kernel_launch(void* const* d_in, const int* in_sizes, int n_in,
                              void* d_out, int out_size, void* d_ws, size_t ws_size,
                              hipStream_t stream)
{
    const float* feat    = (const float*)d_in[0];
    const int*   indices = (const int*)  d_in[1];
    const int*   nbr     = (const int*)  d_in[2];
    const float* W_pre   = (const float*)d_in[3];
    const float* b_pre   = (const float*)d_in[4];
    const float* g_pre   = (const float*)d_in[5];
    const float* be_pre  = (const float*)d_in[6];
    const float* m_pre   = (const float*)d_in[7];
    const float* v_pre   = (const float*)d_in[8];
    const float* Wp1     = (const float*)d_in[9];
    const float* bp1     = (const float*)d_in[10];
    const float* g_pe    = (const float*)d_in[11];
    const float* be_pe   = (const float*)d_in[12];
    const float* m_pe    = (const float*)d_in[13];
    const float* v_pe    = (const float*)d_in[14];
    const float* Wp2     = (const float*)d_in[15];
    const float* bp2     = (const float*)d_in[16];
    const float* W_qkv   = (const float*)d_in[17];
    const float* b_qkv   = (const float*)d_in[18];
    const float* scale_p = (const float*)d_in[19];
    const float* W_dwc   = (const float*)d_in[20];
    const float* b_dwc   = (const float*)d_in[21];
    const float* W_proj  = (const float*)d_in[22];
    const float* b_proj  = (const float*)d_in[23];
    const float* g_n1    = (const float*)d_in[24];
    const float* b_n1    = (const float*)d_in[25];
    float* out = (float*)d_out;

    int N = in_sizes[0] / 64;           // 120000
    size_t NC = (size_t)N * 128;
    float* ws   = (float*)d_ws;
    float* sp   = ws;
    float* qb   = ws + NC;
    float* kb   = ws + 2*NC;
    float* vb   = ws + 3*NC;
    float* ksum = ws + 4*NC;
    float* kvm  = ksum + 128;
    float* xb   = kb;                   // kb is dead after k_red; reuse for conv output

    k_pre <<<N/16, 256, 0, stream>>>(feat, W_pre, b_pre, g_pre, be_pre, m_pre, v_pre, sp, ksum);
    k_qkv <<<N/32, 256, 0, stream>>>(sp, indices, Wp1, bp1, g_pe, be_pe, m_pe, v_pe,
                                     Wp2, bp2, W_qkv, b_qkv, scale_p, qb, kb, vb);
    k_red <<<256,  256, 0, stream>>>(kb, vb, ksum, kvm, N/16);
    k_conv<<<N/64, 256, 0, stream>>>(vb, nbr, W_dwc, b_dwc, xb);
    k_out <<<N/16, 256, 0, stream>>>(xb, qb, ksum, kvm, W_proj, b_proj, sp, g_n1, b_n1, out);
}

// Round 4
// 1240.042 us; speedup vs baseline: 1.9008x; 1.9008x over previous
//
#include <hip/hip_runtime.h>
#include <math.h>

#define EPS 1e-4f
#define BN_EPS 1e-3f
#define LN_EPS 1e-3f

typedef float f32x4 __attribute__((ext_vector_type(4)));
typedef __bf16 bf16x8 __attribute__((ext_vector_type(8)));

__device__ __forceinline__ unsigned int bf16hi_rne(float v){
    unsigned int u = __float_as_uint(v);
    unsigned int r = u + 0x7FFFu + ((u >> 16) & 1u);
    return r & 0xFFFF0000u;                 // bf16(v) bits in top half
}
__device__ __forceinline__ unsigned int pack_hilo(float v){
    unsigned int hi = bf16hi_rne(v);
    float res = v - __uint_as_float(hi);
    unsigned int u2 = __float_as_uint(res);
    unsigned int r2 = u2 + 0x7FFFu + ((u2 >> 16) & 1u);
    return hi | (r2 >> 16);
}
__device__ __forceinline__ f32x4 mfma16(uint4 a, uint4 b, f32x4 c){
    union { uint4 u; bf16x8 v; } A, B;
    A.u = a; B.u = b;
    return __builtin_amdgcn_mfma_f32_16x16x32_bf16(A.v, B.v, c, 0, 0, 0);
}

// ---------------- K1: sp = BN(feat @ W_pre + b_pre)  (+ zero reduction accums) ----------------
__global__ __launch_bounds__(256) void k_pre(
    const float* __restrict__ feat, const float* __restrict__ W_pre,
    const float* __restrict__ b_pre, const float* __restrict__ g_pre,
    const float* __restrict__ be_pre, const float* __restrict__ m_pre,
    const float* __restrict__ v_pre, float* __restrict__ sp,
    float* __restrict__ accums)
{
    __shared__ __align__(16) float ft[16][64];
    int tid = threadIdx.x;
    int r0 = blockIdx.x * 16;
    if (blockIdx.x == 0){
        for (int i = tid; i < 2176; i += 256) accums[i] = 0.f;
    }
    {
        const float4* src = (const float4*)(feat + (size_t)r0 * 64);
        ((float4*)ft)[tid] = src[tid];
    }
    __syncthreads();
    int c = tid & 127;
    int rg = tid >> 7;
    float acc[8] = {0.f,0.f,0.f,0.f,0.f,0.f,0.f,0.f};
    #pragma unroll
    for (int k = 0; k < 64; k += 4){
        float w0 = W_pre[(k+0)*128 + c];
        float w1 = W_pre[(k+1)*128 + c];
        float w2 = W_pre[(k+2)*128 + c];
        float w3 = W_pre[(k+3)*128 + c];
        #pragma unroll
        for (int j = 0; j < 8; j++){
            float4 a = *(const float4*)&ft[rg*8 + j][k];
            acc[j] += a.x*w0 + a.y*w1 + a.z*w2 + a.w*w3;
        }
    }
    float aa = g_pre[c] * rsqrtf(v_pre[c] + BN_EPS);
    float cc = (b_pre[c] - m_pre[c]) * aa + be_pre[c];
    #pragma unroll
    for (int j = 0; j < 8; j++){
        size_t row = r0 + rg*8 + j;
        sp[row*128 + c] = acc[j]*aa + cc;
    }
}

// ---------------- K1b: weight prep — whl_T[t][c][k] = pack(W_dwc[t][k][c]) ----------------
__global__ __launch_bounds__(256) void k_wprep(
    const float* __restrict__ W, unsigned int* __restrict__ whl)
{
    int o = blockIdx.x*256 + threadIdx.x;           // over 27*128*128
    if (o >= 27*128*128) return;
    int k = o & 127; int c = (o >> 7) & 127; int t = o >> 14;
    float v = W[(size_t)((t << 7) + k)*128 + c];
    whl[o] = pack_hilo(v);
}

// ---------------- K2: fused pe + qkv + elementwise (v stored packed hi/lo) ----------------
__global__ __launch_bounds__(256) void k_qkv(
    const float* __restrict__ sp, const int* __restrict__ indices,
    const float* __restrict__ Wp1, const float* __restrict__ bp1,
    const float* __restrict__ g_pe, const float* __restrict__ be_pe,
    const float* __restrict__ m_pe, const float* __restrict__ v_pe,
    const float* __restrict__ Wp2, const float* __restrict__ bp2,
    const float* __restrict__ W_qkv, const float* __restrict__ b_qkv,
    const float* __restrict__ scale_p,
    float* __restrict__ qb, float* __restrict__ kb, unsigned int* __restrict__ vhl)
{
    __shared__ __align__(16) float spt[32][128];
    __shared__ __align__(16) float peh[32][128];
    __shared__ float xyzs[32][3];
    int tid = threadIdx.x;
    int r0 = blockIdx.x * 32;
    {
        const float4* src = (const float4*)(sp + (size_t)r0 * 128);
        float4* dst = (float4*)&spt[0][0];
        #pragma unroll
        for (int u = 0; u < 4; u++) dst[tid + 256*u] = src[tid + 256*u];
    }
    if (tid < 96){
        int r = tid / 3, d = tid % 3;
        xyzs[r][d] = (float)indices[(size_t)(r0 + r)*4 + 1 + d];
    }
    __syncthreads();
    #pragma unroll
    for (int u = 0; u < 16; u++){
        int oi = tid + 256*u;
        int r = oi >> 7, c = oi & 127;
        float dot = xyzs[r][0]*Wp1[c] + xyzs[r][1]*Wp1[128+c] + xyzs[r][2]*Wp1[256+c] + bp1[c];
        float aa = g_pe[c] * rsqrtf(v_pe[c] + BN_EPS);
        float t = (dot - m_pe[c])*aa + be_pe[c];
        peh[r][c] = fmaxf(t, 0.f);
    }
    __syncthreads();
    int c = tid & 127, rg = tid >> 7;
    float accq[16] = {0}, acck[16] = {0}, accv[16] = {0}, accp[16] = {0};
    for (int k = 0; k < 128; k += 4){
        float wq[4], wk[4], wv[4], wp[4];
        #pragma unroll
        for (int i = 0; i < 4; i++){
            wq[i] = W_qkv[(size_t)(k+i)*384 + c];
            wk[i] = W_qkv[(size_t)(k+i)*384 + 128 + c];
            wv[i] = W_qkv[(size_t)(k+i)*384 + 256 + c];
            wp[i] = Wp2[(k+i)*128 + c];
        }
        #pragma unroll
        for (int j = 0; j < 16; j++){
            float4 a = *(const float4*)&spt[rg*16 + j][k];
            accq[j] += a.x*wq[0] + a.y*wq[1] + a.z*wq[2] + a.w*wq[3];
            acck[j] += a.x*wk[0] + a.y*wk[1] + a.z*wk[2] + a.w*wk[3];
            accv[j] += a.x*wv[0] + a.y*wv[1] + a.z*wv[2] + a.w*wv[3];
            float4 p = *(const float4*)&peh[rg*16 + j][k];
            accp[j] += p.x*wp[0] + p.y*wp[1] + p.z*wp[2] + p.w*wp[3];
        }
    }
    float bq = b_qkv[c], bk = b_qkv[128 + c], bv = b_qkv[256 + c], bp = bp2[c];
    float sx = scale_p[c];
    float sc = (sx > 20.f) ? sx : log1pf(expf(sx));
    float inv = 1.f / sc;
    #pragma unroll
    for (int j = 0; j < 16; j++){
        size_t row = r0 + rg*16 + j;
        float pe = accp[j] + bp;
        float qv = (fmaxf(accq[j] + bq, 0.f) + EPS) * inv;
        float kv = (fmaxf(acck[j] + bk + pe, 0.f) + EPS) * inv;
        qb[row*128 + c] = qv;
        kb[row*128 + c] = kv;
        vhl[row*128 + c] = pack_hilo(accv[j] + bv);
    }
}

// ---------------- K2b: ksum[h][e], kv[h][e][f] reductions (v from packed) ----------------
__global__ __launch_bounds__(256) void k_red(
    const float* __restrict__ kb, const unsigned int* __restrict__ vhl,
    float* __restrict__ ksum, float* __restrict__ kvm, int ntiles)
{
    __shared__ __align__(16) float kt[16][128];
    __shared__ __align__(16) unsigned int vt[16][128];
    int tid = threadIdx.x;
    int he = tid & 127, fh = tid >> 7;
    int h = he >> 4;
    float akv[8] = {0,0,0,0,0,0,0,0};
    float aks = 0.f;
    for (int ti = blockIdx.x; ti < ntiles; ti += gridDim.x){
        size_t base = (size_t)ti * 16 * 128;
        const float4* ks_ = (const float4*)(kb + base);
        const uint4* vs_ = (const uint4*)(vhl + base);
        float4* kd = (float4*)&kt[0][0];
        uint4* vd = (uint4*)&vt[0][0];
        __syncthreads();
        kd[tid] = ks_[tid]; kd[tid + 256] = ks_[tid + 256];
        vd[tid] = vs_[tid]; vd[tid + 256] = vs_[tid + 256];
        __syncthreads();
        #pragma unroll 4
        for (int r = 0; r < 16; r++){
            float kval = kt[r][he];
            const unsigned int* vr = &vt[r][h*16 + fh*8];
            #pragma unroll
            for (int j = 0; j < 8; j++){
                unsigned int p = vr[j];
                float vj = __uint_as_float(p & 0xFFFF0000u) + __uint_as_float(p << 16);
                akv[j] += kval * vj;
            }
            if (fh == 0) aks += kval;
        }
    }
    #pragma unroll
    for (int j = 0; j < 8; j++) atomicAdd(&kvm[he*16 + fh*8 + j], akv[j]);
    if (fh == 0) atomicAdd(&ksum[he], aks);
}

// ---------------- K4: 27-tap gather conv via bf16x2-split MFMA ----------------
// 64 rows/block, 256 threads = 4 waves. Wave w owns cols [32w,32w+32).
// A tile (gathered v, packed hi|lo u32) in LDS with XOR granule swizzle;
// B (weights) streamed from packed+transposed whl_T (L2-resident).
__global__ __launch_bounds__(256) void k_conv(
    const unsigned int* __restrict__ vhl, const int* __restrict__ nbr,
    const unsigned int* __restrict__ whl, const float* __restrict__ b_dwc,
    float* __restrict__ xb)
{
    __shared__ __align__(16) unsigned int vt[64*128];   // 32 KB, swizzled
    __shared__ int nbT[27*64];                          // 6.9 KB
    int tid = threadIdx.x;
    int r0 = blockIdx.x * 64;
    for (int i = tid; i < 27*64; i += 256){
        int t = i >> 6, r = i & 63;
        nbT[i] = nbr[(size_t)(r0 + r)*27 + t];
    }
    int lane = tid & 63;
    int w    = tid >> 6;          // wave id 0..3
    int m    = lane & 15;
    int h    = lane >> 4;         // 0..3
    int sw   = m & 7;             // row&7 is m&7 for every row-block
    int tr   = tid >> 5, tc = tid & 31;
    int colbase = w * 32;

    f32x4 acc[4][2];
    #pragma unroll
    for (int rb = 0; rb < 4; rb++)
        #pragma unroll
        for (int cbi = 0; cbi < 2; cbi++)
            acc[rb][cbi] = (f32x4){0.f,0.f,0.f,0.f};

    const unsigned int* bbase0 = whl + ((size_t)(colbase      + m) << 7);
    const unsigned int* bbase1 = whl + ((size_t)(colbase + 16 + m) << 7);

    for (int t = 0; t < 27; t++){
        __syncthreads();
        // ---- gather 64 rows of packed v into swizzled LDS ----
        #pragma unroll
        for (int s = 0; s < 8; s++){
            int r = tr + 8*s;
            int idx = nbT[t*64 + r];
            uint4 val = make_uint4(0u,0u,0u,0u);
            if (idx >= 0) val = *(const uint4*)&vhl[(size_t)idx*128 + tc*4];
            *(uint4*)&vt[r*128 + (((tc ^ (r & 7)) << 2))] = val;
        }
        __syncthreads();
        const unsigned int* bt0 = bbase0 + ((size_t)t << 14);
        const unsigned int* bt1 = bbase1 + ((size_t)t << 14);
        #pragma unroll
        for (int ks = 0; ks < 4; ks++){
            // ---- B fragments (global, L2-resident) ----
            const unsigned int* bp0 = bt0 + ks*32 + h*8;
            const unsigned int* bp1 = bt1 + ks*32 + h*8;
            uint4 b00 = *(const uint4*)bp0;
            uint4 b01 = *(const uint4*)(bp0 + 4);
            uint4 b10 = *(const uint4*)bp1;
            uint4 b11 = *(const uint4*)(bp1 + 4);
            // ---- A fragments (LDS, swizzled) ----
            int G = ks*8 + h*2;
            int offA0 = ((G     ^ sw) << 2);
            int offA1 = (((G+1) ^ sw) << 2);
            uint4 aq[4][2];
            #pragma unroll
            for (int rb = 0; rb < 4; rb++){
                const unsigned int* ap = &vt[(rb*16 + m)*128];
                aq[rb][0] = *(const uint4*)&ap[offA0];
                aq[rb][1] = *(const uint4*)&ap[offA1];
            }
            uint4 ahi[4], alo[4];
            #pragma unroll
            for (int rb = 0; rb < 4; rb++){
                ahi[rb].x = __builtin_amdgcn_perm(aq[rb][0].y, aq[rb][0].x, 0x07060302u);
                ahi[rb].y = __builtin_amdgcn_perm(aq[rb][0].w, aq[rb][0].z, 0x07060302u);
                ahi[rb].z = __builtin_amdgcn_perm(aq[rb][1].y, aq[rb][1].x, 0x07060302u);
                ahi[rb].w = __builtin_amdgcn_perm(aq[rb][1].w, aq[rb][1].z, 0x07060302u);
                alo[rb].x = __builtin_amdgcn_perm(aq[rb][0].y, aq[rb][0].x, 0x05040100u);
                alo[rb].y = __builtin_amdgcn_perm(aq[rb][0].w, aq[rb][0].z, 0x05040100u);
                alo[rb].z = __builtin_amdgcn_perm(aq[rb][1].y, aq[rb][1].x, 0x05040100u);
                alo[rb].w = __builtin_amdgcn_perm(aq[rb][1].w, aq[rb][1].z, 0x05040100u);
            }
            // ---- cbi = 0 ----
            {
                uint4 bhi, blo;
                bhi.x = __builtin_amdgcn_perm(b00.y, b00.x, 0x07060302u);
                bhi.y = __builtin_amdgcn_perm(b00.w, b00.z, 0x07060302u);
                bhi.z = __builtin_amdgcn_perm(b01.y, b01.x, 0x07060302u);
                bhi.w = __builtin_amdgcn_perm(b01.w, b01.z, 0x07060302u);
                blo.x = __builtin_amdgcn_perm(b00.y, b00.x, 0x05040100u);
                blo.y = __builtin_amdgcn_perm(b00.w, b00.z, 0x05040100u);
                blo.z = __builtin_amdgcn_perm(b01.y, b01.x, 0x05040100u);
                blo.w = __builtin_amdgcn_perm(b01.w, b01.z, 0x05040100u);
                #pragma unroll
                for (int rb = 0; rb < 4; rb++){
                    acc[rb][0] = mfma16(ahi[rb], bhi, acc[rb][0]);
                    acc[rb][0] = mfma16(alo[rb], bhi, acc[rb][0]);
                    acc[rb][0] = mfma16(ahi[rb], blo, acc[rb][0]);
                }
            }
            // ---- cbi = 1 ----
            {
                uint4 bhi, blo;
                bhi.x = __builtin_amdgcn_perm(b10.y, b10.x, 0x07060302u);
                bhi.y = __builtin_amdgcn_perm(b10.w, b10.z, 0x07060302u);
                bhi.z = __builtin_amdgcn_perm(b11.y, b11.x, 0x07060302u);
                bhi.w = __builtin_amdgcn_perm(b11.w, b11.z, 0x07060302u);
                blo.x = __builtin_amdgcn_perm(b10.y, b10.x, 0x05040100u);
                blo.y = __builtin_amdgcn_perm(b10.w, b10.z, 0x05040100u);
                blo.z = __builtin_amdgcn_perm(b11.y, b11.x, 0x05040100u);
                blo.w = __builtin_amdgcn_perm(b11.w, b11.z, 0x05040100u);
                #pragma unroll
                for (int rb = 0; rb < 4; rb++){
                    acc[rb][1] = mfma16(ahi[rb], bhi, acc[rb][1]);
                    acc[rb][1] = mfma16(alo[rb], bhi, acc[rb][1]);
                    acc[rb][1] = mfma16(ahi[rb], blo, acc[rb][1]);
                }
            }
        }
    }
    // ---- epilogue: C write (+bias). D: col=lane&15, row=h*4+reg ----
    #pragma unroll
    for (int cbi = 0; cbi < 2; cbi++){
        int col = colbase + cbi*16 + m;
        float bias = b_dwc[col];
        #pragma unroll
        for (int rb = 0; rb < 4; rb++){
            #pragma unroll
            for (int rr = 0; rr < 4; rr++){
                size_t row = (size_t)r0 + rb*16 + h*4 + rr;
                xb[row*128 + col] = acc[rb][cbi][rr] + bias;
            }
        }
    }
}

// ---------------- K5: out = LN( (attn + conv) @ W_proj + b_proj + sp ) ----------------
__global__ __launch_bounds__(256) void k_out(
    const float* __restrict__ xb, const float* __restrict__ qb,
    const float* __restrict__ ksum, const float* __restrict__ kvm,
    const float* __restrict__ W_proj, const float* __restrict__ b_proj,
    const float* __restrict__ sp, const float* __restrict__ g_n1,
    const float* __restrict__ b_n1, float* __restrict__ out)
{
    __shared__ __align__(16) float yt[16][128];
    __shared__ __align__(16) float qt[16][128];
    __shared__ float kvl[2048];
    __shared__ float ksl[128];
    int tid = threadIdx.x;
    int r0 = blockIdx.x * 16;
    {
        const float4* srcy = (const float4*)(xb + (size_t)r0 * 128);
        const float4* srcq = (const float4*)(qb + (size_t)r0 * 128);
        float4* dsty = (float4*)&yt[0][0];
        float4* dstq = (float4*)&qt[0][0];
        dsty[tid] = srcy[tid]; dsty[tid + 256] = srcy[tid + 256];
        dstq[tid] = srcq[tid]; dstq[tid + 256] = srcq[tid + 256];
    }
    #pragma unroll
    for (int u = 0; u < 8; u++) kvl[tid + 256*u] = kvm[tid + 256*u];
    if (tid < 128) ksl[tid] = ksum[tid];
    __syncthreads();

    int c2 = (tid & 63) * 2;
    int rg = tid >> 6;
    {
        int h = c2 >> 4, f0 = c2 & 15;
        float kv0[16], kv1[16], ks[16];
        #pragma unroll
        for (int e = 0; e < 16; e++){
            kv0[e] = kvl[(h*16 + e)*16 + f0];
            kv1[e] = kvl[(h*16 + e)*16 + f0 + 1];
            ks[e]  = ksl[h*16 + e];
        }
        float y[4][2];
        #pragma unroll
        for (int j = 0; j < 4; j++){
            int r = rg*4 + j;
            float zd = 0.f, x0 = 0.f, x1 = 0.f;
            #pragma unroll
            for (int e = 0; e < 16; e++){
                float qe = qt[r][h*16 + e];
                zd += qe * ks[e];
                x0 += qe * kv0[e];
                x1 += qe * kv1[e];
            }
            float iz = 1.f / (zd + EPS);
            y[j][0] = x0*iz + yt[r][c2];
            y[j][1] = x1*iz + yt[r][c2+1];
        }
        #pragma unroll
        for (int j = 0; j < 4; j++){
            yt[rg*4 + j][c2]     = y[j][0];
            yt[rg*4 + j][c2 + 1] = y[j][1];
        }
    }
    __syncthreads();
    float acc[4][2] = {{0,0},{0,0},{0,0},{0,0}};
    for (int k = 0; k < 128; k += 4){
        float2 w0 = *(const float2*)&W_proj[(k+0)*128 + c2];
        float2 w1 = *(const float2*)&W_proj[(k+1)*128 + c2];
        float2 w2 = *(const float2*)&W_proj[(k+2)*128 + c2];
        float2 w3 = *(const float2*)&W_proj[(k+3)*128 + c2];
        #pragma unroll
        for (int j = 0; j < 4; j++){
            float4 a = *(const float4*)&yt[rg*4 + j][k];
            acc[j][0] += a.x*w0.x + a.y*w1.x + a.z*w2.x + a.w*w3.x;
            acc[j][1] += a.x*w0.y + a.y*w1.y + a.z*w2.y + a.w*w3.y;
        }
    }
    float bp0 = b_proj[c2], bp1_ = b_proj[c2+1];
    float g0 = g_n1[c2], g1 = g_n1[c2+1], B0 = b_n1[c2], B1 = b_n1[c2+1];
    float z[4][2], s[4], ss[4];
    #pragma unroll
    for (int j = 0; j < 4; j++){
        size_t row = r0 + rg*4 + j;
        float2 spv = *(const float2*)&sp[row*128 + c2];
        float z0 = acc[j][0] + bp0 + spv.x;
        float z1 = acc[j][1] + bp1_ + spv.y;
        z[j][0] = z0; z[j][1] = z1;
        s[j] = z0 + z1; ss[j] = z0*z0 + z1*z1;
    }
    #pragma unroll
    for (int m = 1; m < 64; m <<= 1){
        #pragma unroll
        for (int j = 0; j < 4; j++){
            s[j]  += __shfl_xor(s[j],  m, 64);
            ss[j] += __shfl_xor(ss[j], m, 64);
        }
    }
    #pragma unroll
    for (int j = 0; j < 4; j++){
        size_t row = r0 + rg*4 + j;
        float mu = s[j] * (1.f/128.f);
        float var = ss[j] * (1.f/128.f) - mu*mu;
        float rstd = rsqrtf(var + LN_EPS);
        float2 o;
        o.x = (z[j][0] - mu)*rstd*g0 + B0;
        o.y = (z[j][1] - mu)*rstd*g1 + B1;
        *(float2*)&out[row*128 + c2] = o;
    }
}

extern "C" void kernel_launch(void* const* d_in, const int* in_sizes, int n_in,
                              void* d_out, int out_size, void* d_ws, size_t ws_size,
                              hipStream_t stream)
{
    const float* feat    = (const float*)d_in[0];
    const int*   indices = (const int*)  d_in[1];
    const int*   nbr     = (const int*)  d_in[2];
    const float* W_pre   = (const float*)d_in[3];
    const float* b_pre   = (const float*)d_in[4];
    const float* g_pre   = (const float*)d_in[5];
    const float* be_pre  = (const float*)d_in[6];
    const float* m_pre   = (const float*)d_in[7];
    const float* v_pre   = (const float*)d_in[8];
    const float* Wp1     = (const float*)d_in[9];
    const float* bp1     = (const float*)d_in[10];
    const float* g_pe    = (const float*)d_in[11];
    const float* be_pe   = (const float*)d_in[12];
    const float* m_pe    = (const float*)d_in[13];
    const float* v_pe    = (const float*)d_in[14];
    const float* Wp2     = (const float*)d_in[15];
    const float* bp2     = (const float*)d_in[16];
    const float* W_qkv   = (const float*)d_in[17];
    const float* b_qkv   = (const float*)d_in[18];
    const float* scale_p = (const float*)d_in[19];
    const float* W_dwc   = (const float*)d_in[20];
    const float* b_dwc   = (const float*)d_in[21];
    const float* W_proj  = (const float*)d_in[22];
    const float* b_proj  = (const float*)d_in[23];
    const float* g_n1    = (const float*)d_in[24];
    const float* b_n1    = (const float*)d_in[25];
    float* out = (float*)d_out;

    int N = in_sizes[0] / 64;           // 120000
    size_t NC = (size_t)N * 128;
    float* ws   = (float*)d_ws;
    float* sp   = ws;
    float* qb   = ws + NC;
    float* kb   = ws + 2*NC;
    unsigned int* vhl = (unsigned int*)(ws + 3*NC);
    float* ksum = ws + 4*NC;
    float* kvm  = ksum + 128;
    unsigned int* whl = (unsigned int*)(ksum + 2176);
    float* xb   = kb;                   // kb dead after k_red; reuse for conv output

    k_wprep<<<1728, 256, 0, stream>>>(W_dwc, whl);
    k_pre  <<<N/16, 256, 0, stream>>>(feat, W_pre, b_pre, g_pre, be_pre, m_pre, v_pre, sp, ksum);
    k_qkv  <<<N/32, 256, 0, stream>>>(sp, indices, Wp1, bp1, g_pe, be_pe, m_pe, v_pe,
                                      Wp2, bp2, W_qkv, b_qkv, scale_p, qb, kb, vhl);
    k_red  <<<256,  256, 0, stream>>>(kb, vhl, ksum, kvm, N/16);
    k_conv <<<N/64, 256, 0, stream>>>(vhl, nbr, whl, b_dwc, xb);
    k_out  <<<N/16, 256, 0, stream>>>(xb, qb, ksum, kvm, W_proj, b_proj, sp, g_n1, b_n1, out);
}

// Round 7
// 1096.220 us; speedup vs baseline: 2.1502x; 1.1312x over previous
//
#include <hip/hip_runtime.h>
#include <math.h>

#define EPS 1e-4f
#define BN_EPS 1e-3f
#define LN_EPS 1e-3f

typedef float f32x4 __attribute__((ext_vector_type(4)));
typedef __bf16 bf16x8 __attribute__((ext_vector_type(8)));

__device__ __forceinline__ unsigned int bf16hi_rne(float v){
    unsigned int u = __float_as_uint(v);
    unsigned int r = u + 0x7FFFu + ((u >> 16) & 1u);
    return r & 0xFFFF0000u;                 // bf16(v) bits in top half
}
__device__ __forceinline__ unsigned int pack_hilo(float v){
    unsigned int hi = bf16hi_rne(v);
    float res = v - __uint_as_float(hi);
    unsigned int u2 = __float_as_uint(res);
    unsigned int r2 = u2 + 0x7FFFu + ((u2 >> 16) & 1u);
    return hi | (r2 >> 16);
}
__device__ __forceinline__ float unpack_hilo(unsigned int p){
    return __uint_as_float(p & 0xFFFF0000u) + __uint_as_float(p << 16);
}
__device__ __forceinline__ f32x4 mfma16(uint4 a, uint4 b, f32x4 c){
    union { uint4 u; bf16x8 v; } A, B;
    A.u = a; B.u = b;
    return __builtin_amdgcn_mfma_f32_16x16x32_bf16(A.v, B.v, c, 0, 0, 0);
}

// ---------------- K1: sp_hl = pack(BN(feat @ W_pre + b_pre))  (+ zero reduction accums) ----------------
__global__ __launch_bounds__(256) void k_pre(
    const float* __restrict__ feat, const float* __restrict__ W_pre,
    const float* __restrict__ b_pre, const float* __restrict__ g_pre,
    const float* __restrict__ be_pre, const float* __restrict__ m_pre,
    const float* __restrict__ v_pre, unsigned int* __restrict__ sphl,
    float* __restrict__ accums)
{
    __shared__ __align__(16) float ft[16][64];
    int tid = threadIdx.x;
    int r0 = blockIdx.x * 16;
    if (blockIdx.x == 0){
        for (int i = tid; i < 2176; i += 256) accums[i] = 0.f;
    }
    {
        const float4* src = (const float4*)(feat + (size_t)r0 * 64);
        ((float4*)ft)[tid] = src[tid];
    }
    __syncthreads();
    int c = tid & 127;
    int rg = tid >> 7;
    float acc[8] = {0.f,0.f,0.f,0.f,0.f,0.f,0.f,0.f};
    #pragma unroll
    for (int k = 0; k < 64; k += 4){
        float w0 = W_pre[(k+0)*128 + c];
        float w1 = W_pre[(k+1)*128 + c];
        float w2 = W_pre[(k+2)*128 + c];
        float w3 = W_pre[(k+3)*128 + c];
        #pragma unroll
        for (int j = 0; j < 8; j++){
            float4 a = *(const float4*)&ft[rg*8 + j][k];
            acc[j] += a.x*w0 + a.y*w1 + a.z*w2 + a.w*w3;
        }
    }
    float aa = g_pre[c] * rsqrtf(v_pre[c] + BN_EPS);
    float cc = (b_pre[c] - m_pre[c]) * aa + be_pre[c];
    #pragma unroll
    for (int j = 0; j < 8; j++){
        size_t row = r0 + rg*8 + j;
        sphl[row*128 + c] = pack_hilo(acc[j]*aa + cc);
    }
}

// ---------------- K1b: weight prep — whl_T[t][c][k] = pack(W_dwc[t][k][c])  (verified round-3) ----------------
__global__ __launch_bounds__(256) void k_wprep(
    const float* __restrict__ W, unsigned int* __restrict__ whl)
{
    int o = blockIdx.x*256 + threadIdx.x;           // over 27*128*128
    if (o >= 27*128*128) return;
    int k = o & 127; int c = (o >> 7) & 127; int t = o >> 14;
    float v = W[(size_t)((t << 7) + k)*128 + c];
    whl[o] = pack_hilo(v);
}

// ---------------- K1c: qkv/pe weight prep -> split-plane k-octet units ----------------
// unit index = col*16 + koct (col 0-127:q, 128-255:k, 256-383:v, 384-511:pe);
// hi plane at [u], lo plane at [8192+u].
__global__ __launch_bounds__(256) void k_wprep2(
    const float* __restrict__ Wqkv, const float* __restrict__ Wp2,
    uint4* __restrict__ qwhl)
{
    int o = blockIdx.x*256 + threadIdx.x;           // 512*16 = 8192
    if (o >= 8192) return;
    int koct = o & 15, col = o >> 4;
    float v[8];
    #pragma unroll
    for (int j = 0; j < 8; j++){
        int k = koct*8 + j;
        v[j] = (col < 384) ? Wqkv[(size_t)k*384 + col] : Wp2[(size_t)k*128 + (col - 384)];
    }
    unsigned int hi[4], lo[4];
    #pragma unroll
    for (int j2 = 0; j2 < 4; j2++){
        float a = v[2*j2], b = v[2*j2+1];
        unsigned int ha = bf16hi_rne(a), hb = bf16hi_rne(b);
        float ra = a - __uint_as_float(ha);
        float rb = b - __uint_as_float(hb);
        hi[j2] = (ha >> 16) | (hb & 0xFFFF0000u);
        lo[j2] = (bf16hi_rne(ra) >> 16) | (bf16hi_rne(rb) & 0xFFFF0000u);
    }
    qwhl[o]        = make_uint4(hi[0],hi[1],hi[2],hi[3]);
    qwhl[8192 + o] = make_uint4(lo[0],lo[1],lo[2],lo[3]);
}

// ---------------- K2: fused pe + qkv via split-bf16 MFMA ----------------
// 32 rows/block, 4 waves: w0=q, w1=k, w2=v, w3=pe(@Wp2). pe -> LDS -> k epilogue.
// A tiles (sp_hl / pe_hl) in LDS stride-132 (2-way bank alias = free). No prefetch.
__global__ __launch_bounds__(256) void k_qkv(
    const unsigned int* __restrict__ sphl, const int* __restrict__ indices,
    const float* __restrict__ Wp1, const float* __restrict__ bp1,
    const float* __restrict__ g_pe, const float* __restrict__ be_pe,
    const float* __restrict__ m_pe, const float* __restrict__ v_pe,
    const float* __restrict__ bp2, const uint4* __restrict__ qwhl,
    const float* __restrict__ b_qkv, const float* __restrict__ scale_p,
    float* __restrict__ qb, float* __restrict__ kb, unsigned int* __restrict__ vhl)
{
    __shared__ __align__(16) unsigned int At[2][32*132];  // [0]=sp_hl, [1]=pe_hl
    __shared__ float peout[32*128];
    __shared__ float invs[128];
    __shared__ float xyzs[32][3];
    int tid = threadIdx.x;
    int r0 = blockIdx.x * 32;
    {
        const uint4* src = (const uint4*)(sphl + (size_t)r0*128);
        #pragma unroll
        for (int u = 0; u < 4; u++){
            int i = tid + 256*u;            // 1024 uint4 = 32x128 u32
            int r = i >> 5, cq = i & 31;
            *(uint4*)&At[0][r*132 + cq*4] = src[i];
        }
    }
    if (tid < 96){
        int r = tid / 3, d = tid % 3;
        xyzs[r][d] = (float)indices[(size_t)(r0 + r)*4 + 1 + d];
    }
    if (tid < 128){
        float sx = scale_p[tid];
        float sc = (sx > 20.f) ? sx : log1pf(expf(sx));
        invs[tid] = 1.f / sc;
    }
    __syncthreads();
    #pragma unroll
    for (int u = 0; u < 16; u++){
        int oi = tid + 256*u;               // 4096 = 32x128
        int r = oi >> 7, c = oi & 127;
        float dot = xyzs[r][0]*Wp1[c] + xyzs[r][1]*Wp1[128+c] + xyzs[r][2]*Wp1[256+c] + bp1[c];
        float aa = g_pe[c] * rsqrtf(v_pe[c] + BN_EPS);
        float t = (dot - m_pe[c])*aa + be_pe[c];
        At[1][r*132 + c] = pack_hilo(fmaxf(t, 0.f));
    }
    __syncthreads();

    int lane = tid & 63;
    int w = tid >> 6;                       // 0=q 1=k 2=v 3=pe
    int m = lane & 15, kq = lane >> 4;      // A row group / k-quarter
    const unsigned int* A = &At[w == 3 ? 1 : 0][0];

    // A fragments [rt][ks], hi/lo (verified perm idiom)
    uint4 ahi[2][4], alo[2][4];
    #pragma unroll
    for (int rt = 0; rt < 2; rt++){
        #pragma unroll
        for (int ks = 0; ks < 4; ks++){
            const unsigned int* ap = &A[(rt*16 + m)*132 + ks*32 + kq*8];
            uint4 a0 = *(const uint4*)ap;
            uint4 a1 = *(const uint4*)(ap + 4);
            uint4 h, l;
            h.x = __builtin_amdgcn_perm(a0.y, a0.x, 0x07060302u);
            h.y = __builtin_amdgcn_perm(a0.w, a0.z, 0x07060302u);
            h.z = __builtin_amdgcn_perm(a1.y, a1.x, 0x07060302u);
            h.w = __builtin_amdgcn_perm(a1.w, a1.z, 0x07060302u);
            l.x = __builtin_amdgcn_perm(a0.y, a0.x, 0x05040100u);
            l.y = __builtin_amdgcn_perm(a0.w, a0.z, 0x05040100u);
            l.z = __builtin_amdgcn_perm(a1.y, a1.x, 0x05040100u);
            l.w = __builtin_amdgcn_perm(a1.w, a1.z, 0x05040100u);
            ahi[rt][ks] = h; alo[rt][ks] = l;
        }
    }

    f32x4 acc[2][8];
    #pragma unroll
    for (int rt = 0; rt < 2; rt++)
        #pragma unroll
        for (int ct = 0; ct < 8; ct++)
            acc[rt][ct] = (f32x4){0.f,0.f,0.f,0.f};

    int colg = w * 128;                     // wave's column group in qwhl
    #pragma unroll
    for (int ct = 0; ct < 8; ct++){
        #pragma unroll
        for (int ks = 0; ks < 4; ks++){
            int bu = (colg + ct*16 + m)*16 + ks*4 + kq;
            uint4 bhi = qwhl[bu];
            uint4 blo = qwhl[8192 + bu];
            #pragma unroll
            for (int rt = 0; rt < 2; rt++){
                acc[rt][ct] = mfma16(ahi[rt][ks], bhi, acc[rt][ct]);
                acc[rt][ct] = mfma16(alo[rt][ks], bhi, acc[rt][ct]);
                acc[rt][ct] = mfma16(ahi[rt][ks], blo, acc[rt][ct]);
            }
        }
    }

    // ---- epilogue. D: col=lane&15, row=(lane>>4)*4+reg ----
    if (w == 3){
        #pragma unroll
        for (int ct = 0; ct < 8; ct++){
            int col = ct*16 + m;
            float bp = bp2[col];
            #pragma unroll
            for (int rt = 0; rt < 2; rt++){
                #pragma unroll
                for (int reg = 0; reg < 4; reg++){
                    int row = rt*16 + kq*4 + reg;
                    peout[row*128 + col] = acc[rt][ct][reg] + bp;
                }
            }
        }
    }
    __syncthreads();
    if (w == 0){
        #pragma unroll
        for (int ct = 0; ct < 8; ct++){
            int col = ct*16 + m;
            float bq = b_qkv[col], inv = invs[col];
            #pragma unroll
            for (int rt = 0; rt < 2; rt++){
                #pragma unroll
                for (int reg = 0; reg < 4; reg++){
                    int row = rt*16 + kq*4 + reg;
                    float v = acc[rt][ct][reg] + bq;
                    qb[(size_t)(r0 + row)*128 + col] = (fmaxf(v, 0.f) + EPS) * inv;
                }
            }
        }
    } else if (w == 1){
        #pragma unroll
        for (int ct = 0; ct < 8; ct++){
            int col = ct*16 + m;
            float bk = b_qkv[128 + col], inv = invs[col];
            #pragma unroll
            for (int rt = 0; rt < 2; rt++){
                #pragma unroll
                for (int reg = 0; reg < 4; reg++){
                    int row = rt*16 + kq*4 + reg;
                    float v = acc[rt][ct][reg] + bk + peout[row*128 + col];
                    kb[(size_t)(r0 + row)*128 + col] = (fmaxf(v, 0.f) + EPS) * inv;
                }
            }
        }
    } else if (w == 2){
        #pragma unroll
        for (int ct = 0; ct < 8; ct++){
            int col = ct*16 + m;
            float bv = b_qkv[256 + col];
            #pragma unroll
            for (int rt = 0; rt < 2; rt++){
                #pragma unroll
                for (int reg = 0; reg < 4; reg++){
                    int row = rt*16 + kq*4 + reg;
                    vhl[(size_t)(r0 + row)*128 + col] = pack_hilo(acc[rt][ct][reg] + bv);
                }
            }
        }
    }
}

// ---------------- K2b: ksum[h][e], kv[h][e][f] reductions (v from packed) ----------------
__global__ __launch_bounds__(256) void k_red(
    const float* __restrict__ kb, const unsigned int* __restrict__ vhl,
    float* __restrict__ ksum, float* __restrict__ kvm, int ntiles)
{
    __shared__ __align__(16) float kt[16][128];
    __shared__ __align__(16) unsigned int vt[16][128];
    int tid = threadIdx.x;
    int he = tid & 127, fh = tid >> 7;
    int h = he >> 4;
    float akv[8] = {0,0,0,0,0,0,0,0};
    float aks = 0.f;
    for (int ti = blockIdx.x; ti < ntiles; ti += gridDim.x){
        size_t base = (size_t)ti * 16 * 128;
        const float4* ks_ = (const float4*)(kb + base);
        const uint4* vs_ = (const uint4*)(vhl + base);
        float4* kd = (float4*)&kt[0][0];
        uint4* vd = (uint4*)&vt[0][0];
        __syncthreads();
        kd[tid] = ks_[tid]; kd[tid + 256] = ks_[tid + 256];
        vd[tid] = vs_[tid]; vd[tid + 256] = vs_[tid + 256];
        __syncthreads();
        #pragma unroll 4
        for (int r = 0; r < 16; r++){
            float kval = kt[r][he];
            const unsigned int* vr = &vt[r][h*16 + fh*8];
            #pragma unroll
            for (int j = 0; j < 8; j++){
                akv[j] += kval * unpack_hilo(vr[j]);
            }
            if (fh == 0) aks += kval;
        }
    }
    #pragma unroll
    for (int j = 0; j < 8; j++) atomicAdd(&kvm[he*16 + fh*8 + j], akv[j]);
    if (fh == 0) atomicAdd(&ksum[he], aks);
}

// ---------------- K4: 27-tap gather conv via bf16x2-split MFMA (verified round-3 version) ----------------
__global__ __launch_bounds__(256) void k_conv(
    const unsigned int* __restrict__ vhl, const int* __restrict__ nbr,
    const unsigned int* __restrict__ whl, const float* __restrict__ b_dwc,
    float* __restrict__ xb)
{
    __shared__ __align__(16) unsigned int vt[64*128];   // 32 KB, swizzled
    __shared__ int nbT[27*64];                          // 6.9 KB
    int tid = threadIdx.x;
    int r0 = blockIdx.x * 64;
    for (int i = tid; i < 27*64; i += 256){
        int t = i >> 6, r = i & 63;
        nbT[i] = nbr[(size_t)(r0 + r)*27 + t];
    }
    int lane = tid & 63;
    int w    = tid >> 6;          // wave id 0..3
    int m    = lane & 15;
    int h    = lane >> 4;         // 0..3
    int sw   = m & 7;
    int tr   = tid >> 5, tc = tid & 31;
    int colbase = w * 32;

    f32x4 acc[4][2];
    #pragma unroll
    for (int rb = 0; rb < 4; rb++)
        #pragma unroll
        for (int cbi = 0; cbi < 2; cbi++)
            acc[rb][cbi] = (f32x4){0.f,0.f,0.f,0.f};

    const unsigned int* bbase0 = whl + ((size_t)(colbase      + m) << 7);
    const unsigned int* bbase1 = whl + ((size_t)(colbase + 16 + m) << 7);

    for (int t = 0; t < 27; t++){
        __syncthreads();
        #pragma unroll
        for (int s = 0; s < 8; s++){
            int r = tr + 8*s;
            int idx = nbT[t*64 + r];
            uint4 val = make_uint4(0u,0u,0u,0u);
            if (idx >= 0) val = *(const uint4*)&vhl[(size_t)idx*128 + tc*4];
            *(uint4*)&vt[r*128 + (((tc ^ (r & 7)) << 2))] = val;
        }
        __syncthreads();
        const unsigned int* bt0 = bbase0 + ((size_t)t << 14);
        const unsigned int* bt1 = bbase1 + ((size_t)t << 14);
        #pragma unroll
        for (int ks = 0; ks < 4; ks++){
            const unsigned int* bp0 = bt0 + ks*32 + h*8;
            const unsigned int* bp1 = bt1 + ks*32 + h*8;
            uint4 b00 = *(const uint4*)bp0;
            uint4 b01 = *(const uint4*)(bp0 + 4);
            uint4 b10 = *(const uint4*)bp1;
            uint4 b11 = *(const uint4*)(bp1 + 4);
            int G = ks*8 + h*2;
            int offA0 = ((G     ^ sw) << 2);
            int offA1 = (((G+1) ^ sw) << 2);
            uint4 aq[4][2];
            #pragma unroll
            for (int rb = 0; rb < 4; rb++){
                const unsigned int* ap = &vt[(rb*16 + m)*128];
                aq[rb][0] = *(const uint4*)&ap[offA0];
                aq[rb][1] = *(const uint4*)&ap[offA1];
            }
            uint4 ahi[4], alo[4];
            #pragma unroll
            for (int rb = 0; rb < 4; rb++){
                ahi[rb].x = __builtin_amdgcn_perm(aq[rb][0].y, aq[rb][0].x, 0x07060302u);
                ahi[rb].y = __builtin_amdgcn_perm(aq[rb][0].w, aq[rb][0].z, 0x07060302u);
                ahi[rb].z = __builtin_amdgcn_perm(aq[rb][1].y, aq[rb][1].x, 0x07060302u);
                ahi[rb].w = __builtin_amdgcn_perm(aq[rb][1].w, aq[rb][1].z, 0x07060302u);
                alo[rb].x = __builtin_amdgcn_perm(aq[rb][0].y, aq[rb][0].x, 0x05040100u);
                alo[rb].y = __builtin_amdgcn_perm(aq[rb][0].w, aq[rb][0].z, 0x05040100u);
                alo[rb].z = __builtin_amdgcn_perm(aq[rb][1].y, aq[rb][1].x, 0x05040100u);
                alo[rb].w = __builtin_amdgcn_perm(aq[rb][1].w, aq[rb][1].z, 0x05040100u);
            }
            {
                uint4 bhi, blo;
                bhi.x = __builtin_amdgcn_perm(b00.y, b00.x, 0x07060302u);
                bhi.y = __builtin_amdgcn_perm(b00.w, b00.z, 0x07060302u);
                bhi.z = __builtin_amdgcn_perm(b01.y, b01.x, 0x07060302u);
                bhi.w = __builtin_amdgcn_perm(b01.w, b01.z, 0x07060302u);
                blo.x = __builtin_amdgcn_perm(b00.y, b00.x, 0x05040100u);
                blo.y = __builtin_amdgcn_perm(b00.w, b00.z, 0x05040100u);
                blo.z = __builtin_amdgcn_perm(b01.y, b01.x, 0x05040100u);
                blo.w = __builtin_amdgcn_perm(b01.w, b01.z, 0x05040100u);
                #pragma unroll
                for (int rb = 0; rb < 4; rb++){
                    acc[rb][0] = mfma16(ahi[rb], bhi, acc[rb][0]);
                    acc[rb][0] = mfma16(alo[rb], bhi, acc[rb][0]);
                    acc[rb][0] = mfma16(ahi[rb], blo, acc[rb][0]);
                }
            }
            {
                uint4 bhi, blo;
                bhi.x = __builtin_amdgcn_perm(b10.y, b10.x, 0x07060302u);
                bhi.y = __builtin_amdgcn_perm(b10.w, b10.z, 0x07060302u);
                bhi.z = __builtin_amdgcn_perm(b11.y, b11.x, 0x07060302u);
                bhi.w = __builtin_amdgcn_perm(b11.w, b11.z, 0x07060302u);
                blo.x = __builtin_amdgcn_perm(b10.y, b10.x, 0x05040100u);
                blo.y = __builtin_amdgcn_perm(b10.w, b10.z, 0x05040100u);
                blo.z = __builtin_amdgcn_perm(b11.y, b11.x, 0x05040100u);
                blo.w = __builtin_amdgcn_perm(b11.w, b11.z, 0x05040100u);
                #pragma unroll
                for (int rb = 0; rb < 4; rb++){
                    acc[rb][1] = mfma16(ahi[rb], bhi, acc[rb][1]);
                    acc[rb][1] = mfma16(alo[rb], bhi, acc[rb][1]);
                    acc[rb][1] = mfma16(ahi[rb], blo, acc[rb][1]);
                }
            }
        }
    }
    #pragma unroll
    for (int cbi = 0; cbi < 2; cbi++){
        int col = colbase + cbi*16 + m;
        float bias = b_dwc[col];
        f32x4* a = (cbi == 0) ? nullptr : nullptr; (void)a;
        #pragma unroll
        for (int rb = 0; rb < 4; rb++){
            #pragma unroll
            for (int rr = 0; rr < 4; rr++){
                size_t row = (size_t)r0 + rb*16 + h*4 + rr;
                xb[row*128 + col] = ((cbi == 0) ? acc[rb][0][rr] : acc[rb][1][rr]) + bias;
            }
        }
    }
}

// ---------------- K5: out = LN( (attn + conv) @ W_proj + b_proj + sp ) ----------------
__global__ __launch_bounds__(256) void k_out(
    const float* __restrict__ xb, const float* __restrict__ qb,
    const float* __restrict__ ksum, const float* __restrict__ kvm,
    const float* __restrict__ W_proj, const float* __restrict__ b_proj,
    const unsigned int* __restrict__ sphl, const float* __restrict__ g_n1,
    const float* __restrict__ b_n1, float* __restrict__ out)
{
    __shared__ __align__(16) float yt[16][128];
    __shared__ __align__(16) float qt[16][128];
    __shared__ float kvl[2048];
    __shared__ float ksl[128];
    int tid = threadIdx.x;
    int r0 = blockIdx.x * 16;
    {
        const float4* srcy = (const float4*)(xb + (size_t)r0 * 128);
        const float4* srcq = (const float4*)(qb + (size_t)r0 * 128);
        float4* dsty = (float4*)&yt[0][0];
        float4* dstq = (float4*)&qt[0][0];
        dsty[tid] = srcy[tid]; dsty[tid + 256] = srcy[tid + 256];
        dstq[tid] = srcq[tid]; dstq[tid + 256] = srcq[tid + 256];
    }
    #pragma unroll
    for (int u = 0; u < 8; u++) kvl[tid + 256*u] = kvm[tid + 256*u];
    if (tid < 128) ksl[tid] = ksum[tid];
    __syncthreads();

    int c2 = (tid & 63) * 2;
    int rg = tid >> 6;
    {
        int h = c2 >> 4, f0 = c2 & 15;
        float kv0[16], kv1[16], ks[16];
        #pragma unroll
        for (int e = 0; e < 16; e++){
            kv0[e] = kvl[(h*16 + e)*16 + f0];
            kv1[e] = kvl[(h*16 + e)*16 + f0 + 1];
            ks[e]  = ksl[h*16 + e];
        }
        float y[4][2];
        #pragma unroll
        for (int j = 0; j < 4; j++){
            int r = rg*4 + j;
            float zd = 0.f, x0 = 0.f, x1 = 0.f;
            #pragma unroll
            for (int e = 0; e < 16; e++){
                float qe = qt[r][h*16 + e];
                zd += qe * ks[e];
                x0 += qe * kv0[e];
                x1 += qe * kv1[e];
            }
            float iz = 1.f / (zd + EPS);
            y[j][0] = x0*iz + yt[r][c2];
            y[j][1] = x1*iz + yt[r][c2+1];
        }
        #pragma unroll
        for (int j = 0; j < 4; j++){
            yt[rg*4 + j][c2]     = y[j][0];
            yt[rg*4 + j][c2 + 1] = y[j][1];
        }
    }
    __syncthreads();
    float acc[4][2] = {{0,0},{0,0},{0,0},{0,0}};
    for (int k = 0; k < 128; k += 4){
        float2 w0 = *(const float2*)&W_proj[(k+0)*128 + c2];
        float2 w1 = *(const float2*)&W_proj[(k+1)*128 + c2];
        float2 w2 = *(const float2*)&W_proj[(k+2)*128 + c2];
        float2 w3 = *(const float2*)&W_proj[(k+3)*128 + c2];
        #pragma unroll
        for (int j = 0; j < 4; j++){
            float4 a = *(const float4*)&yt[rg*4 + j][k];
            acc[j][0] += a.x*w0.x + a.y*w1.x + a.z*w2.x + a.w*w3.x;
            acc[j][1] += a.x*w0.y + a.y*w1.y + a.z*w2.y + a.w*w3.y;
        }
    }
    float bp0 = b_proj[c2], bp1_ = b_proj[c2+1];
    float g0 = g_n1[c2], g1 = g_n1[c2+1], B0 = b_n1[c2], B1 = b_n1[c2+1];
    float z[4][2], s[4], ss[4];
    #pragma unroll
    for (int j = 0; j < 4; j++){
        size_t row = r0 + rg*4 + j;
        uint2 spv = *(const uint2*)&sphl[row*128 + c2];
        float z0 = acc[j][0] + bp0 + unpack_hilo(spv.x);
        float z1 = acc[j][1] + bp1_ + unpack_hilo(spv.y);
        z[j][0] = z0; z[j][1] = z1;
        s[j] = z0 + z1; ss[j] = z0*z0 + z1*z1;
    }
    #pragma unroll
    for (int m = 1; m < 64; m <<= 1){
        #pragma unroll
        for (int j = 0; j < 4; j++){
            s[j]  += __shfl_xor(s[j],  m, 64);
            ss[j] += __shfl_xor(ss[j], m, 64);
        }
    }
    #pragma unroll
    for (int j = 0; j < 4; j++){
        size_t row = r0 + rg*4 + j;
        float mu = s[j] * (1.f/128.f);
        float var = ss[j] * (1.f/128.f) - mu*mu;
        float rstd = rsqrtf(var + LN_EPS);
        float2 o;
        o.x = (z[j][0] - mu)*rstd*g0 + B0;
        o.y = (z[j][1] - mu)*rstd*g1 + B1;
        *(float2*)&out[row*128 + c2] = o;
    }
}

extern "C" void kernel_launch(void* const* d_in, const int* in_sizes, int n_in,
                              void* d_out, int out_size, void* d_ws, size_t ws_size,
                              hipStream_t stream)
{
    const float* feat    = (const float*)d_in[0];
    const int*   indices = (const int*)  d_in[1];
    const int*   nbr     = (const int*)  d_in[2];
    const float* W_pre   = (const float*)d_in[3];
    const float* b_pre   = (const float*)d_in[4];
    const float* g_pre   = (const float*)d_in[5];
    const float* be_pre  = (const float*)d_in[6];
    const float* m_pre   = (const float*)d_in[7];
    const float* v_pre   = (const float*)d_in[8];
    const float* Wp1     = (const float*)d_in[9];
    const float* bp1     = (const float*)d_in[10];
    const float* g_pe    = (const float*)d_in[11];
    const float* be_pe   = (const float*)d_in[12];
    const float* m_pe    = (const float*)d_in[13];
    const float* v_pe    = (const float*)d_in[14];
    const float* Wp2     = (const float*)d_in[15];
    const float* bp2     = (const float*)d_in[16];
    const float* W_qkv   = (const float*)d_in[17];
    const float* b_qkv   = (const float*)d_in[18];
    const float* scale_p = (const float*)d_in[19];
    const float* W_dwc   = (const float*)d_in[20];
    const float* b_dwc   = (const float*)d_in[21];
    const float* W_proj  = (const float*)d_in[22];
    const float* b_proj  = (const float*)d_in[23];
    const float* g_n1    = (const float*)d_in[24];
    const float* b_n1    = (const float*)d_in[25];
    float* out = (float*)d_out;

    int N = in_sizes[0] / 64;           // 120000
    size_t NC = (size_t)N * 128;
    float* ws   = (float*)d_ws;
    unsigned int* sphl = (unsigned int*)ws;
    float* qb   = ws + NC;
    float* kb   = ws + 2*NC;
    unsigned int* vhl = (unsigned int*)(ws + 3*NC);
    float* ksum = ws + 4*NC;
    float* kvm  = ksum + 128;
    unsigned int* whl = (unsigned int*)(ksum + 2560);   // 27*128*128 u32 = 1.77MB
    uint4* qwhl = (uint4*)(whl + 27*128*128);           // 16384 uint4 = 256KB
    float* xb   = kb;                   // kb dead after k_red; reuse for conv output

    k_wprep <<<1728, 256, 0, stream>>>(W_dwc, whl);
    k_wprep2<<<32,   256, 0, stream>>>(W_qkv, Wp2, qwhl);
    k_pre   <<<N/16, 256, 0, stream>>>(feat, W_pre, b_pre, g_pre, be_pre, m_pre, v_pre, sphl, ksum);
    k_qkv   <<<N/32, 256, 0, stream>>>(sphl, indices, Wp1, bp1, g_pe, be_pe, m_pe, v_pe,
                                       bp2, qwhl, b_qkv, scale_p, qb, kb, vhl);
    k_red   <<<256,  256, 0, stream>>>(kb, vhl, ksum, kvm, N/16);
    k_conv  <<<N/64, 256, 0, stream>>>(vhl, nbr, whl, b_dwc, xb);
    k_out   <<<N/16, 256, 0, stream>>>(xb, qb, ksum, kvm, W_proj, b_proj, sphl, g_n1, b_n1, out);
}